// Round 14
// baseline (128.642 us; speedup 1.0000x reference)
//
#include <hip/hip_runtime.h>

#define HD 256
#define LN_EPS 1e-5f
#define DEG_EPS 1e-6f
#define CAP 64
#define C2 264

typedef __attribute__((ext_vector_type(8))) short short8;
typedef __attribute__((ext_vector_type(4))) short s16x4;
typedef __attribute__((ext_vector_type(4))) float f32x4;
typedef __attribute__((ext_vector_type(4))) int i32x4;

__device__ inline unsigned short f2bf(float f) {
    union { float f; unsigned int u; } v; v.f = f;
    unsigned int r = v.u + 0x7FFFu + ((v.u >> 16) & 1u);
    return (unsigned short)(r >> 16);
}
__device__ inline float bf2f(unsigned short h) {
    union { unsigned int u; float f; } v; v.u = ((unsigned int)h) << 16;
    return v.f;
}

// Blocks [0,zb): zero counts. Blocks [zb, zb+256): W12 = W2[:, :256]@W1
// (fp32 accumulate -> bf16), bv = W2@b1, ucol = clue column of W2.
__global__ __launch_bounds__(256) void prep0_kernel(
    int* __restrict__ counts, int num_con,
    const float* __restrict__ msg_W, const float* __restrict__ msg_b,
    const float* __restrict__ upd_W,
    unsigned short* __restrict__ w12b, float* __restrict__ bv,
    float* __restrict__ ucol, int zb) {
    int b = blockIdx.x, tid = threadIdx.x;
    if (b < zb) {
        int i = (b * 256 + tid) * 4;
        if (i + 4 <= num_con) *(i32x4*)(counts + i) = (i32x4){0, 0, 0, 0};
        else for (; i < num_con; ++i) counts[i] = 0;
    } else {
        int j = b - zb, k = tid;
        // 4 independent partial accumulators -> deeper load pipeline
        float a0 = 0.f, a1 = 0.f, a2 = 0.f, a3 = 0.f, accb = 0.f;
#pragma unroll 2
        for (int m = 0; m < 256; m += 4) {
            float w0 = upd_W[j * 257 + m + 0];
            float w1 = upd_W[j * 257 + m + 1];
            float w2 = upd_W[j * 257 + m + 2];
            float w3 = upd_W[j * 257 + m + 3];
            a0 = fmaf(w0, msg_W[(m + 0) * 256 + k], a0);
            a1 = fmaf(w1, msg_W[(m + 1) * 256 + k], a1);
            a2 = fmaf(w2, msg_W[(m + 2) * 256 + k], a2);
            a3 = fmaf(w3, msg_W[(m + 3) * 256 + k], a3);
            accb = fmaf(w0, msg_b[m + 0], accb);
            accb = fmaf(w1, msg_b[m + 1], accb);
            accb = fmaf(w2, msg_b[m + 2], accb);
            accb = fmaf(w3, msg_b[m + 3], accb);
        }
        w12b[j * 256 + k] = f2bf((a0 + a1) + (a2 + a3));
        if (k == 0) { bv[j] = accb; ucol[j] = upd_W[j * 257 + 256]; }
    }
}

// x fp32 -> bf16, grid-strided (Guideline 11: ~2048 blocks, many
// independent iterations per thread -> 12+ loads in flight).
__global__ __launch_bounds__(256) void xcast_kernel(
    const float* __restrict__ x, unsigned short* __restrict__ xb, long n) {
    long stride = (long)gridDim.x * 256;
    long t0 = (long)blockIdx.x * 256 + threadIdx.x;
#pragma unroll 1
    for (long i = t0 * 8; i + 8 <= n; i += stride * 8) {
        float4 u0 = *(const float4*)(x + i);
        float4 u1 = *(const float4*)(x + i + 4);
        short8 o;
        o[0] = (short)f2bf(u0.x); o[1] = (short)f2bf(u0.y);
        o[2] = (short)f2bf(u0.z); o[3] = (short)f2bf(u0.w);
        o[4] = (short)f2bf(u1.x); o[5] = (short)f2bf(u1.y);
        o[6] = (short)f2bf(u1.z); o[7] = (short)f2bf(u1.w);
        *(short8*)(xb + i) = o;
    }
    // tail (n divisible by 8 for H=256 inputs; keep for safety)
    if (t0 == 0) for (long i = n & ~7L; i < n; ++i) xb[i] = f2bf(x[i]);
}

// Bucket edges by dst: counts[] = degree, eidx[d*CAP + p] = src ids.
__global__ __launch_bounds__(256) void fill_kernel(
    const int* __restrict__ src, const int* __restrict__ dst,
    int* __restrict__ counts, int* __restrict__ eidx, int E) {
    int e = blockIdx.x * 256 + threadIdx.x;
    if (e >= E) return;
    int d = dst[e];
    int p = atomicAdd(&counts[d], 1);
    if (p < CAP) eidx[d * CAP + p] = src[e];
}

// 4 waves/block, each wave processes 4 rows sequentially -> 16 rows/block,
// 3125 blocks (was 12.5K single-row waves). batch-8 loads in flight.
__global__ __launch_bounds__(256) void gather_kernel(
    const unsigned short* __restrict__ xb, const int* __restrict__ counts,
    const int* __restrict__ eidx, unsigned short* __restrict__ agg,
    int num_con) {
    int wv   = threadIdx.x >> 6;
    int lane = threadIdx.x & 63;
#pragma unroll 1
    for (int r = 0; r < 4; ++r) {
        int row = blockIdx.x * 16 + wv * 4 + r;
        if (row >= num_con) continue;
        int cnt = counts[row];
        int cgo = min(cnt, CAP);
        int sid = (lane < cgo) ? eidx[row * CAP + lane] : 0;
        float a0 = 0.f, a1 = 0.f, a2 = 0.f, a3 = 0.f;
#pragma unroll 1
        for (int i = 0; i < cgo; i += 8) {
            int s[8];
#pragma unroll
            for (int u = 0; u < 8; ++u) s[u] = __shfl(sid, i + u, 64);
            s16x4 v[8];
#pragma unroll
            for (int u = 0; u < 8; ++u)
                v[u] = *(const s16x4*)(xb + (long)s[u] * HD + lane * 4);
#pragma unroll
            for (int u = 0; u < 8; ++u) {
                float wg = (i + u < cgo) ? 1.f : 0.f;
                a0 = fmaf(bf2f((unsigned short)v[u][0]), wg, a0);
                a1 = fmaf(bf2f((unsigned short)v[u][1]), wg, a1);
                a2 = fmaf(bf2f((unsigned short)v[u][2]), wg, a2);
                a3 = fmaf(bf2f((unsigned short)v[u][3]), wg, a3);
            }
        }
        float sc = 1.0f / ((float)cnt + DEG_EPS);
        s16x4 o;
        o[0] = (short)f2bf(a0 * sc); o[1] = (short)f2bf(a1 * sc);
        o[2] = (short)f2bf(a2 * sc); o[3] = (short)f2bf(a3 * sc);
        *(s16x4*)(agg + (long)row * HD + lane * 4) = o;
    }
}

// Single fused GEMM:
// out = LN(relu(agg @ W12^T + tcoef*bv + ucol*clue + b2)) * ln_w + ln_b.
// 4 waves; wave w holds W12 rows [w*64,+64) in 128 VGPR. A-tile staged
// cooperatively in XOR-swizzled LDS once per tile. Grid-stride 16-row tiles.
__global__ __launch_bounds__(256) void gfinal_kernel(
    const unsigned short* __restrict__ agg, const int* __restrict__ counts,
    const float* __restrict__ clue,
    const unsigned short* __restrict__ w12b, const float* __restrict__ bv,
    const float* __restrict__ ucol, const float* __restrict__ upd_b,
    const float* __restrict__ ln_w, const float* __restrict__ ln_b,
    float* __restrict__ out, int num_con, int ntiles) {

    __shared__ unsigned short sA[16 * 256];   // 8 KB, XOR-swizzled rows
    __shared__ float sZ[2][16 * C2];
    const int tid = threadIdx.x, w = tid >> 6, lane = tid & 63;
    const int lr = lane & 15, lg = lane >> 4;

    short8 bfr[4][8];
#pragma unroll
    for (int jt = 0; jt < 4; ++jt)
#pragma unroll
        for (int ks = 0; ks < 8; ++ks)
            bfr[jt][ks] = *(const short8*)(w12b + (w * 64 + jt * 16 + lr) * HD + lg * 8 + ks * 32);
    float uc[4], b2[4], bvv[4];
#pragma unroll
    for (int jt = 0; jt < 4; ++jt) {
        uc[jt]  = ucol[w * 64 + jt * 16 + lr];
        b2[jt]  = upd_b[w * 64 + jt * 16 + lr];
        bvv[jt] = bv[w * 64 + jt * 16 + lr];
    }
    const int seg = tid & 15;
    f32x4 lw[4], lb[4];
#pragma unroll
    for (int k = 0; k < 4; ++k) {
        lw[k] = *(const f32x4*)(ln_w + seg * 16 + k * 4);
        lb[k] = *(const f32x4*)(ln_b + seg * 16 + k * 4);
    }
    const int srow = tid >> 4, scol = (tid & 15) * 16;

    int buf = 0;
#pragma unroll 1
    for (int rt = blockIdx.x; rt < ntiles; rt += gridDim.x) {
        int r0 = rt * 16;
        {
            int arc = min(r0 + srow, num_con - 1);
            const unsigned short* gp = agg + (long)arc * HD + scol;
            short8 v0 = *(const short8*)(gp);
            short8 v1 = *(const short8*)(gp + 8);
            int b0 = (srow * 512 + scol * 2) ^ ((srow & 7) << 4);
            int b1 = (srow * 512 + scol * 2 + 16) ^ ((srow & 7) << 4);
            *(short8*)((char*)sA + b0) = v0;
            *(short8*)((char*)sA + b1) = v1;
        }
        __syncthreads();

        short8 af[8];
#pragma unroll
        for (int ks = 0; ks < 8; ++ks) {
            int byte = (lr * 512 + (ks * 32 + lg * 8) * 2) ^ ((lr & 7) << 4);
            af[ks] = *(const short8*)((char*)sA + byte);
        }

        f32x4 acc[4] = {{0.f,0.f,0.f,0.f},{0.f,0.f,0.f,0.f},{0.f,0.f,0.f,0.f},{0.f,0.f,0.f,0.f}};
#pragma unroll
        for (int ks = 0; ks < 8; ++ks)
#pragma unroll
            for (int jt = 0; jt < 4; ++jt)
                acc[jt] = __builtin_amdgcn_mfma_f32_16x16x32_bf16(af[ks], bfr[jt][ks], acc[jt], 0, 0, 0);

        float cl[4], trow[4];
#pragma unroll
        for (int q = 0; q < 4; ++q) {
            int rr = min(r0 + lg * 4 + q, num_con - 1);
            cl[q] = clue[rr];
            float dvq = (float)counts[rr];
            trow[q] = dvq / (dvq + DEG_EPS);
        }
#pragma unroll
        for (int jt = 0; jt < 4; ++jt)
#pragma unroll
            for (int q = 0; q < 4; ++q) {
                float z = fmaxf(acc[jt][q] + trow[q] * bvv[jt] + uc[jt] * cl[q] + b2[jt], 0.0f);
                sZ[buf][(lg * 4 + q) * C2 + w * 64 + jt * 16 + lr] = z;
            }
        __syncthreads();
        {
            int row = tid >> 4;
            const float* zp = &sZ[buf][row * C2 + seg * 16];
            f32x4 z4[4];
            float s = 0.f, s2 = 0.f;
#pragma unroll
            for (int k = 0; k < 4; ++k) {
                z4[k] = *(const f32x4*)(zp + k * 4);
#pragma unroll
                for (int e = 0; e < 4; ++e) { s += z4[k][e]; s2 += z4[k][e] * z4[k][e]; }
            }
#pragma unroll
            for (int m = 1; m < 16; m <<= 1) {
                s  += __shfl_xor(s,  m, 64);
                s2 += __shfl_xor(s2, m, 64);
            }
            float mu = s * (1.0f / HD);
            float var = s2 * (1.0f / HD) - mu * mu;
            float rs = rsqrtf(var + LN_EPS);
            int grow = r0 + row;
            if (grow < num_con) {
                float* gp = out + (long)grow * HD + seg * 16;
#pragma unroll
                for (int k = 0; k < 4; ++k) {
                    f32x4 o;
#pragma unroll
                    for (int e = 0; e < 4; ++e)
                        o[e] = (z4[k][e] - mu) * rs * lw[k][e] + lb[k][e];
                    *(f32x4*)(gp + k * 4) = o;
                }
            }
        }
        buf ^= 1;
    }
}

extern "C" void kernel_launch(void* const* d_in, const int* in_sizes, int n_in,
                              void* d_out, int out_size, void* d_ws, size_t ws_size,
                              hipStream_t stream) {
    const float* x_var = (const float*)d_in[0];
    const int*   src   = (const int*)d_in[1];
    const int*   dst   = (const int*)d_in[2];
    const float* clue  = (const float*)d_in[3];
    // d_in[4] = num_con scalar (derived from out_size instead)
    const float* msg_W = (const float*)d_in[5];
    const float* msg_b = (const float*)d_in[6];
    const float* upd_W = (const float*)d_in[7];
    const float* upd_b = (const float*)d_in[8];
    const float* ln_w  = (const float*)d_in[9];
    const float* ln_b  = (const float*)d_in[10];

    int E = in_sizes[1];
    long n_x = in_sizes[0];
    int n_var = (int)(n_x / HD);
    int num_con = out_size / HD;
    int ntiles = (num_con + 15) / 16;

    char* ws = (char*)d_ws;
    int* counts = (int*)ws;                               // num_con ints
    int* eidx   = (int*)(ws + (((size_t)num_con * 4 + 255) & ~(size_t)255));
    char* after = (char*)(eidx + (size_t)num_con * CAP);  // num_con*CAP ints
    size_t xoff = ((size_t)(after - ws) + 255) & ~(size_t)255;
    unsigned short* xb = (unsigned short*)(ws + xoff);    // n_var*256 bf16
    size_t aoff = (xoff + (size_t)n_var * HD * 2 + 255) & ~(size_t)255;
    unsigned short* agg = (unsigned short*)(ws + aoff);   // num_con*256 bf16
    size_t woff = (aoff + (size_t)num_con * HD * 2 + 255) & ~(size_t)255;
    unsigned short* w12b = (unsigned short*)(ws + woff);  // 256*256 bf16
    float* bvp  = (float*)(w12b + 256 * 256);             // 256 fp32
    float* ucol = bvp + 256;                              // 256 fp32

    int zb = (num_con + 1023) / 1024;
    prep0_kernel<<<zb + 256, 256, 0, stream>>>(
        counts, num_con, msg_W, msg_b, upd_W, w12b, bvp, ucol, zb);

    xcast_kernel<<<2048, 256, 0, stream>>>(x_var, xb, n_x);

    fill_kernel<<<(E + 255) / 256, 256, 0, stream>>>(src, dst, counts, eidx, E);

    gather_kernel<<<(num_con + 15) / 16, 256, 0, stream>>>(
        xb, counts, eidx, agg, num_con);

    gfinal_kernel<<<1024, 256, 0, stream>>>(
        agg, counts, clue, w12b, bvp, ucol, upd_b, ln_w, ln_b,
        (float*)d_out, num_con, ntiles);
}